// Round 10
// baseline (186.441 us; speedup 1.0000x reference)
//
#include <hip/hip_runtime.h>
#include <math.h>

// Problem constants (fixed by reference setup_inputs)
constexpr int B = 2, C = 16, H = 160, W = 192, S = 3, D = 48;
constexpr int HW = H * W;          // 30720 = 120 * 256
constexpr int SB = S * B;
constexpr int ND = 2;              // depths per thread (pairing)
constexpr int G = D / ND;          // 24 depth groups

// ------------------------------------------------------------------
// Setup kernel: per (s,b) fold projection chain into
//   A = Ks * R * inv(Kref) (3x3 f64), q = Ks * t (f64)
// so main kernel does p = depth*(A*[u,v,1]) + q.
// ws layout: (s*B+b)*12 doubles = [A row-major 0..8][q 9..11]
// ------------------------------------------------------------------
__global__ void precompute_mats(const float* __restrict__ ref_intr,
                                const float* __restrict__ src_intr,
                                const float* __restrict__ ref_to_src,
                                double* __restrict__ ws)
{
    const int i = threadIdx.x;
    if (i >= SB) return;
    const int b = i % B;

    const float* Kp = ref_intr + b * 9;
    const double a00 = Kp[0], a01 = Kp[1], a02 = Kp[2];
    const double a10 = Kp[3], a11 = Kp[4], a12 = Kp[5];
    const double a20 = Kp[6], a21 = Kp[7], a22 = Kp[8];
    const double c00 =  (a11 * a22 - a12 * a21);
    const double c01 = -(a10 * a22 - a12 * a20);
    const double c02 =  (a10 * a21 - a11 * a20);
    const double c10 = -(a01 * a22 - a02 * a21);
    const double c11 =  (a00 * a22 - a02 * a20);
    const double c12 = -(a00 * a21 - a01 * a20);
    const double c20 =  (a01 * a12 - a02 * a11);
    const double c21 = -(a00 * a12 - a02 * a10);
    const double c22 =  (a00 * a11 - a01 * a10);
    const double invdet = 1.0 / (a00 * c00 + a01 * c01 + a02 * c02);
    const double iK[9] = { c00 * invdet, c10 * invdet, c20 * invdet,
                           c01 * invdet, c11 * invdet, c21 * invdet,
                           c02 * invdet, c12 * invdet, c22 * invdet };

    const float* Tp = ref_to_src + i * 16;
    const float* Ks = src_intr + i * 9;

    double M[9];  // R * inv(K)
    #pragma unroll
    for (int r = 0; r < 3; ++r)
        #pragma unroll
        for (int c = 0; c < 3; ++c)
            M[r * 3 + c] = (double)Tp[r * 4 + 0] * iK[0 + c]
                         + (double)Tp[r * 4 + 1] * iK[3 + c]
                         + (double)Tp[r * 4 + 2] * iK[6 + c];

    double* o = ws + i * 12;
    #pragma unroll
    for (int r = 0; r < 3; ++r) {
        #pragma unroll
        for (int c = 0; c < 3; ++c)
            o[r * 3 + c] = (double)Ks[r * 3 + 0] * M[0 + c]
                         + (double)Ks[r * 3 + 1] * M[3 + c]
                         + (double)Ks[r * 3 + 2] * M[6 + c];
        o[9 + r] = (double)Ks[r * 3 + 0] * (double)Tp[3]
                 + (double)Ks[r * 3 + 1] * (double)Tp[7]
                 + (double)Ks[r * 3 + 2] * (double)Tp[11];
    }
}

// ------------------------------------------------------------------
// Main kernel. 2D grid (Round-4 win): blockIdx.y = b*G+dg keeps b/dg/s
// provably wave-uniform -> depth/mats/channel-bases scalarize. NCHW
// stride-1 coalesced loads (Round-3 lesson: NHWC gathers amplify L1
// transactions ~4x). NO min-waves __launch_bounds__ (Rounds 2&5 HARD
// RULE: forced caps -> catastrophic scratch spills).
//
// Round-9: ND=2 sharing is proven (-27% issue/output, R7/R8) but VGPR
// 100-128 kept it in the 4-wave tier. This round removes the f1[16]
// always-live block with two exact folds:
//  * n1^2 = Σr² - sum1*m1  (single pass; n1 well-conditioned ~4,
//    subtracted term ~Σr²/16 -> no cancellation risk; the fragile
//    quantity in this problem is n2, handled by the shifted form).
//  * dot = Σr·val - m1·Σval, with Σval = st + C·av free from the
//    shifted-variance accumulators. r_c reloaded per channel (L1-hot,
//    same addresses every s). Error scale identical to the validated
//    R5/R6 dot form.
// And caps the scheduler's load-hoisting window (R7->R8 lesson: spare
// regs get spent on prefetch depth): c=0 peeled (compile-time shift),
// then #pragma unroll 3 over c=1..15. Target: <=64 VGPR (8-wave tier).
// ------------------------------------------------------------------
__global__ __launch_bounds__(256) void plane_sweep_kernel(
    const float* __restrict__ ref_feats,   // [B,C,H,W]
    const float* __restrict__ src_feats,   // [S,B,C,H,W]
    const float* __restrict__ depths,      // [D]
    const double* __restrict__ mats,       // [SB][12]
    float* __restrict__ out)               // [B,D,H,W]
{
    const int pix = blockIdx.x * 256 + threadIdx.x;   // HW = 120*256 exact
    const int by  = blockIdx.y;                       // b*G + dg (scalar)
    const int dg  = by % G;                           // scalar
    const int b   = by / G;                           // scalar

    const int w = pix % W;
    const int h = pix / W;

    // ---- ref stats WITHOUT storing f1: m1, n1 in one pass ----
    const float* rb = ref_feats + (size_t)b * C * HW;
    float sum1 = 0.0f, sqr1 = 0.0f;
    #pragma unroll
    for (int c = 0; c < C; ++c) {
        const float rc = rb[c * HW + pix];
        sum1 += rc;
        sqr1 = fmaf(rc, rc, sqr1);
    }
    const float m1 = sum1 * (1.0f / C);
    float sq1 = fmaf(-sum1, m1, sqr1);     // Σ(r-m1)² = Σr² - sum1·m1
    sq1 = fmaxf(sq1, 0.0f);
    const float n1 = sqrtf(sq1);

    const double u = (double)w, v = (double)h;
    const double dep0 = (double)depths[dg * ND + 0];   // scalar loads
    const double dep1 = (double)depths[dg * ND + 1];

    float cost0 = 0.0f, cost1 = 0.0f;   // named accumulators (rule #20)

    #pragma unroll 1   // one source live at a time; s uniform
    for (int s = 0; s < S; ++s) {
        const double* Aq = mats + (s * B + b) * 12;   // scalar loads
        const double rx = fma(u, Aq[0], fma(v, Aq[1], Aq[2]));
        const double ry = fma(u, Aq[3], fma(v, Aq[4], Aq[5]));
        const double rz = fma(u, Aq[6], fma(v, Aq[7], Aq[8]));
        const double q0 = Aq[9], q1 = Aq[10], q2 = Aq[11];

        // ---- phase 1: geometry for both depths -> named scalars ----
        auto geom = [&](double depth,
                        float& w00, float& w01, float& w10, float& w11,
                        int& o00, int& o01, int& o10, int& o11) {
            const double p0 = fma(depth, rx, q0);
            const double p1 = fma(depth, ry, q1);
            const double p2 = fma(depth, rz, q2);

            const bool valid = p2 > 0.001;
            const double zs = fmax(p2, 0.001);
            // f64 reciprocal: v_rcp_f64 approx + 1 Newton step (>=2^-28 rel)
#if __has_builtin(__builtin_amdgcn_rcp)
            double r = __builtin_amdgcn_rcp(zs);
#else
            double r = (double)__builtin_amdgcn_rcpf((float)zs);
            r = r * fma(-zs, r, 2.0);
#endif
            r = r * fma(-zs, r, 2.0);
            const double x = p0 * r;
            const double y = p1 * r;

            const double x0f = floor(x);
            const double y0f = floor(y);
            // sub-pixel fractions -> f32 (f64 x,y already ~1e-12-accurate)
            const float fx = (float)(x - x0f);
            const float fy = (float)(y - y0f);
            const int x0 = (int)x0f;
            const int y0 = (int)y0f;
            const int x1 = x0 + 1;
            const int y1 = y0 + 1;

            const float gx = 1.0f - fx, gy = 1.0f - fy;
            const bool okx0 = (x0 >= 0) & (x0 < W);
            const bool okx1 = (x1 >= 0) & (x1 < W);
            const bool oky0 = (y0 >= 0) & (y0 < H);
            const bool oky1 = (y1 >= 0) & (y1 < H);
            w00 = (valid & okx0 & oky0) ? gx * gy : 0.0f;
            w01 = (valid & okx1 & oky0) ? fx * gy : 0.0f;
            w10 = (valid & okx0 & oky1) ? gx * fy : 0.0f;
            w11 = (valid & okx1 & oky1) ? fx * fy : 0.0f;

            const int x0c = min(max(x0, 0), W - 1);
            const int x1c = min(max(x1, 0), W - 1);
            const int y0c = min(max(y0, 0), H - 1);
            const int y1c = min(max(y1, 0), H - 1);
            o00 = y0c * W + x0c;
            o01 = y0c * W + x1c;
            o10 = y1c * W + x0c;
            o11 = y1c * W + x1c;
        };

        float wa00, wa01, wa10, wa11, wb00, wb01, wb10, wb11;
        int   oa00, oa01, oa10, oa11, ob00, ob01, ob10, ob11;
        geom(dep0, wa00, wa01, wa10, wa11, oa00, oa01, oa10, oa11);
        geom(dep1, wb00, wb01, wb10, wb11, ob00, ob01, ob10, ob11);

        // sb wave-uniform -> saddr loads; channel walks in SALU
        const float* sb = src_feats + (size_t)(s * B + b) * C * HW;

        // ---- phase 2: ONE merged fused pass for both depths ----
        // c = 0 peeled so the shift init stays compile-time under
        // partial unroll.
        float rdot0, st0 = 0.0f, s20 = 0.0f, av0;
        float rdot1, st1 = 0.0f, s21 = 0.0f, av1;
        {
            const float rc = rb[pix];
            const float val0 = wa00 * sb[oa00] + wa01 * sb[oa01]
                             + wa10 * sb[oa10] + wa11 * sb[oa11];
            const float val1 = wb00 * sb[ob00] + wb01 * sb[ob01]
                             + wb10 * sb[ob10] + wb11 * sb[ob11];
            av0 = val0; av1 = val1;
            rdot0 = rc * val0;
            rdot1 = rc * val1;
        }
        #pragma unroll 3   // 15 = 3*5 exact; bounds the load-hoist window
        for (int c = 1; c < C; ++c) {
            const float* p = sb + c * HW;
            const float rc = rb[c * HW + pix];
            const float va00 = p[oa00];
            const float va01 = p[oa01];
            const float va10 = p[oa10];
            const float va11 = p[oa11];
            const float vb00 = p[ob00];
            const float vb01 = p[ob01];
            const float vb10 = p[ob10];
            const float vb11 = p[ob11];
            const float val0 = wa00 * va00 + wa01 * va01 + wa10 * va10 + wa11 * va11;
            const float val1 = wb00 * vb00 + wb01 * vb01 + wb10 * vb10 + wb11 * vb11;
            const float t0 = val0 - av0;
            st0 += t0;
            s20 = fmaf(t0, t0, s20);
            const float t1 = val1 - av1;
            st1 += t1;
            s21 = fmaf(t1, t1, s21);
            rdot0 = fmaf(rc, val0, rdot0);
            rdot1 = fmaf(rc, val1, rdot1);
        }
        // Σval = st + C·av ; dot = Σr·val - m1·Σval ;
        // Σ(f2-m2)² = s2 - st²/C  (shifted form; clamp rounding negatives)
        const float sv0 = fmaf((float)C, av0, st0);
        const float dot0 = fmaf(-m1, sv0, rdot0);
        float sq20 = fmaf(-st0 * (1.0f / C), st0, s20);
        sq20 = fmaxf(sq20, 0.0f);
        cost0 += dot0 / (n1 * sqrtf(sq20) + 1e-6f);

        const float sv1 = fmaf((float)C, av1, st1);
        const float dot1 = fmaf(-m1, sv1, rdot1);
        float sq21 = fmaf(-st1 * (1.0f / C), st1, s21);
        sq21 = fmaxf(sq21, 0.0f);
        cost1 += dot1 / (n1 * sqrtf(sq21) + 1e-6f);
    }

    // out base wave-uniform -> saddr stores with voffset pix*4
    float* op = out + (size_t)(b * D + dg * ND) * HW + pix;
    op[0]  = cost0 * (1.0f / S);
    op[HW] = cost1 * (1.0f / S);
}

extern "C" void kernel_launch(void* const* d_in, const int* in_sizes, int n_in,
                              void* d_out, int out_size, void* d_ws, size_t ws_size,
                              hipStream_t stream) {
    const float* ref_feats  = (const float*)d_in[0];
    const float* src_feats  = (const float*)d_in[1];
    const float* ref_intr   = (const float*)d_in[2];
    const float* src_intr   = (const float*)d_in[3];
    const float* ref_to_src = (const float*)d_in[4];
    const float* depths     = (const float*)d_in[5];
    float* out = (float*)d_out;
    double* mats = (double*)d_ws;   // needs SB*12*8 = 576 bytes

    precompute_mats<<<1, 64, 0, stream>>>(ref_intr, src_intr, ref_to_src, mats);

    dim3 grid(HW / 256, B * G);     // 120 x 48, exact
    plane_sweep_kernel<<<grid, dim3(256), 0, stream>>>(
        ref_feats, src_feats, depths, mats, out);
}

// Round 11
// 161.560 us; speedup vs baseline: 1.1540x; 1.1540x over previous
//
#include <hip/hip_runtime.h>
#include <math.h>

// Problem constants (fixed by reference setup_inputs)
constexpr int B = 2, C = 16, H = 160, W = 192, S = 3, D = 48;
constexpr int HW = H * W;          // 30720 = 120 * 256
constexpr int SB = S * B;

// ------------------------------------------------------------------
// Setup kernel: per (s,b) fold projection chain into
//   A = Ks * R * inv(Kref) (3x3 f64), q = Ks * t (f64)
// so main kernel does p = depth*(A*[u,v,1]) + q.
// ws layout: (s*B+b)*12 doubles = [A row-major 0..8][q 9..11]
// ------------------------------------------------------------------
__global__ void precompute_mats(const float* __restrict__ ref_intr,
                                const float* __restrict__ src_intr,
                                const float* __restrict__ ref_to_src,
                                double* __restrict__ ws)
{
    const int i = threadIdx.x;
    if (i >= SB) return;
    const int b = i % B;

    const float* Kp = ref_intr + b * 9;
    const double a00 = Kp[0], a01 = Kp[1], a02 = Kp[2];
    const double a10 = Kp[3], a11 = Kp[4], a12 = Kp[5];
    const double a20 = Kp[6], a21 = Kp[7], a22 = Kp[8];
    const double c00 =  (a11 * a22 - a12 * a21);
    const double c01 = -(a10 * a22 - a12 * a20);
    const double c02 =  (a10 * a21 - a11 * a20);
    const double c10 = -(a01 * a22 - a02 * a21);
    const double c11 =  (a00 * a22 - a02 * a20);
    const double c12 = -(a00 * a21 - a01 * a20);
    const double c20 =  (a01 * a12 - a02 * a11);
    const double c21 = -(a00 * a12 - a02 * a10);
    const double c22 =  (a00 * a11 - a01 * a10);
    const double invdet = 1.0 / (a00 * c00 + a01 * c01 + a02 * c02);
    const double iK[9] = { c00 * invdet, c10 * invdet, c20 * invdet,
                           c01 * invdet, c11 * invdet, c21 * invdet,
                           c02 * invdet, c12 * invdet, c22 * invdet };

    const float* Tp = ref_to_src + i * 16;
    const float* Ks = src_intr + i * 9;

    double M[9];  // R * inv(K)
    #pragma unroll
    for (int r = 0; r < 3; ++r)
        #pragma unroll
        for (int c = 0; c < 3; ++c)
            M[r * 3 + c] = (double)Tp[r * 4 + 0] * iK[0 + c]
                         + (double)Tp[r * 4 + 1] * iK[3 + c]
                         + (double)Tp[r * 4 + 2] * iK[6 + c];

    double* o = ws + i * 12;
    #pragma unroll
    for (int r = 0; r < 3; ++r) {
        #pragma unroll
        for (int c = 0; c < 3; ++c)
            o[r * 3 + c] = (double)Ks[r * 3 + 0] * M[0 + c]
                         + (double)Ks[r * 3 + 1] * M[3 + c]
                         + (double)Ks[r * 3 + 2] * M[6 + c];
        o[9 + r] = (double)Ks[r * 3 + 0] * (double)Tp[3]
                 + (double)Ks[r * 3 + 1] * (double)Tp[7]
                 + (double)Ks[r * 3 + 2] * (double)Tp[11];
    }
}

// ------------------------------------------------------------------
// Main kernel. 2D grid (Round-4 win): blockIdx.y = b*D+d keeps b/d/s
// provably wave-uniform -> depth/mats/channel-bases scalarize (saddr
// loads, SALU walks). NCHW stride-1 coalesced (Round-3 lesson). NO
// min-waves __launch_bounds__ (Rounds 2&5 HARD RULE: forced caps ->
// catastrophic scratch spills). ND-sharing abandoned (R7/R8/R10:
// three packagings, all lost to R6 via regs or MLP throttling).
//
// Round-11 experiment: ND=1 + f1-fold + FULL unroll. Tests whether R6
// (92% reported VALUBusy) is secretly latency-bound: static instr
// count says ~2200 cyc/wave but measured busy-cycles/wave = 5437 —
// 2.5x unexplained. This variant removes the f1[16] always-live block
// (R10-validated exact folds: n1^2 = Σr²-sum1·m1; dot = Σrc·val -
// m1·Σval with Σval = st + C·av free) targeting ~44-52 VGPR = the
// 10-waves/SIMD tier (+25% residency over R6), while full unroll
// keeps R6's deep load window (R10 lesson: unroll-3 vmcnt fences
// killed MLP, 63% busy). If this loses to R6: revert to R6, kernel is
// issue-bound, done.
// ------------------------------------------------------------------
__global__ __launch_bounds__(256) void plane_sweep_kernel(
    const float* __restrict__ ref_feats,   // [B,C,H,W]
    const float* __restrict__ src_feats,   // [S,B,C,H,W]
    const float* __restrict__ depths,      // [D]
    const double* __restrict__ mats,       // [SB][12]
    float* __restrict__ out)               // [B,D,H,W]
{
    const int pix = blockIdx.x * 256 + threadIdx.x;   // HW = 120*256 exact
    const int by  = blockIdx.y;                       // b*D + d (scalar)
    const int d   = by % D;                           // scalar
    const int b   = by / D;                           // scalar

    const int w = pix % W;
    const int h = pix / W;

    // ---- ref stats WITHOUT storing f1: m1, n1 in one pass ----
    const float* rb = ref_feats + (size_t)b * C * HW;
    float sum1 = 0.0f, sqr1 = 0.0f;
    #pragma unroll
    for (int c = 0; c < C; ++c) {
        const float rc = rb[c * HW + pix];
        sum1 += rc;
        sqr1 = fmaf(rc, rc, sqr1);
    }
    const float m1 = sum1 * (1.0f / C);
    float sq1 = fmaf(-sum1, m1, sqr1);     // Σ(r-m1)² = Σr² - sum1·m1
    sq1 = fmaxf(sq1, 0.0f);
    const float n1 = sqrtf(sq1);

    const double u = (double)w, v = (double)h;
    const double depth = (double)depths[d];    // scalar load
    float cost = 0.0f;

    #pragma unroll 1   // one source's f64 state live at a time; s uniform
    for (int s = 0; s < S; ++s) {
        const double* Aq = mats + (s * B + b) * 12;   // scalar loads
        const double rx = fma(u, Aq[0], fma(v, Aq[1], Aq[2]));
        const double ry = fma(u, Aq[3], fma(v, Aq[4], Aq[5]));
        const double rz = fma(u, Aq[6], fma(v, Aq[7], Aq[8]));

        const double p0 = fma(depth, rx, Aq[9]);
        const double p1 = fma(depth, ry, Aq[10]);
        const double p2 = fma(depth, rz, Aq[11]);

        const bool valid = p2 > 0.001;
        const double zs = fmax(p2, 0.001);
        // f64 reciprocal: v_rcp_f64 approx + 1 Newton step (>=2^-28 rel)
#if __has_builtin(__builtin_amdgcn_rcp)
        double r = __builtin_amdgcn_rcp(zs);
#else
        double r = (double)__builtin_amdgcn_rcpf((float)zs);
        r = r * fma(-zs, r, 2.0);
#endif
        r = r * fma(-zs, r, 2.0);
        const double x = p0 * r;
        const double y = p1 * r;

        const double x0f = floor(x);
        const double y0f = floor(y);
        // sub-pixel fractions -> f32 (f64 x,y already ~1e-12-accurate)
        const float fx = (float)(x - x0f);
        const float fy = (float)(y - y0f);
        const int x0 = (int)x0f;
        const int y0 = (int)y0f;
        const int x1 = x0 + 1;
        const int y1 = y0 + 1;

        const float gx = 1.0f - fx, gy = 1.0f - fy;
        const bool okx0 = (x0 >= 0) & (x0 < W);
        const bool okx1 = (x1 >= 0) & (x1 < W);
        const bool oky0 = (y0 >= 0) & (y0 < H);
        const bool oky1 = (y1 >= 0) & (y1 < H);
        const float w00 = (valid & okx0 & oky0) ? gx * gy : 0.0f;
        const float w01 = (valid & okx1 & oky0) ? fx * gy : 0.0f;
        const float w10 = (valid & okx0 & oky1) ? gx * fy : 0.0f;
        const float w11 = (valid & okx1 & oky1) ? fx * fy : 0.0f;

        const int x0c = min(max(x0, 0), W - 1);
        const int x1c = min(max(x1, 0), W - 1);
        const int y0c = min(max(y0, 0), H - 1);
        const int y1c = min(max(y1, 0), H - 1);
        const int off00 = y0c * W + x0c;
        const int off01 = y0c * W + x1c;
        const int off10 = y1c * W + x0c;
        const int off11 = y1c * W + x1c;

        // sb wave-uniform -> saddr loads; channel walks in SALU
        const float* sb = src_feats + (size_t)(s * B + b) * C * HW;

        // ---- fused pass: bilinear + shifted-variance stats + rdot ----
        // c = 0 peeled (compile-time shift init).
        float rdot, st = 0.0f, s2 = 0.0f, av;
        {
            const float rc = rb[pix];
            const float val = w00 * sb[off00] + w01 * sb[off01]
                            + w10 * sb[off10] + w11 * sb[off11];
            av = val;
            rdot = rc * val;
        }
        #pragma unroll   // FULL unroll: deep load window (R10 lesson)
        for (int c = 1; c < C; ++c) {
            const float* p = sb + c * HW;
            const float rc = rb[c * HW + pix];
            const float v00 = p[off00];
            const float v01 = p[off01];
            const float v10 = p[off10];
            const float v11 = p[off11];
            const float val = w00 * v00 + w01 * v01 + w10 * v10 + w11 * v11;
            const float t = val - av;
            st += t;
            s2 = fmaf(t, t, s2);
            rdot = fmaf(rc, val, rdot);
        }
        // Σval = st + C·av ; dot = Σrc·val - m1·Σval ;
        // Σ(f2-m2)² = s2 - st²/C (shifted form; clamp rounding negatives)
        const float sv = fmaf((float)C, av, st);
        const float dot = fmaf(-m1, sv, rdot);
        float sq2 = fmaf(-st * (1.0f / C), st, s2);
        sq2 = fmaxf(sq2, 0.0f);
        cost += dot / (n1 * sqrtf(sq2) + 1e-6f);
    }

    // out base wave-uniform -> saddr store with voffset pix*4
    out[(size_t)by * HW + pix] = cost * (1.0f / S);
}

extern "C" void kernel_launch(void* const* d_in, const int* in_sizes, int n_in,
                              void* d_out, int out_size, void* d_ws, size_t ws_size,
                              hipStream_t stream) {
    const float* ref_feats  = (const float*)d_in[0];
    const float* src_feats  = (const float*)d_in[1];
    const float* ref_intr   = (const float*)d_in[2];
    const float* src_intr   = (const float*)d_in[3];
    const float* ref_to_src = (const float*)d_in[4];
    const float* depths     = (const float*)d_in[5];
    float* out = (float*)d_out;
    double* mats = (double*)d_ws;   // needs SB*12*8 = 576 bytes

    precompute_mats<<<1, 64, 0, stream>>>(ref_intr, src_intr, ref_to_src, mats);

    dim3 grid(HW / 256, B * D);     // 120 x 96, exact
    plane_sweep_kernel<<<grid, dim3(256), 0, stream>>>(
        ref_feats, src_feats, depths, mats, out);
}